// Round 3
// baseline (234.577 us; speedup 1.0000x reference)
//
#include <hip/hip_runtime.h>

// LIF recurrence, T=4, TAU=1.0, THRESH=1.0.
// mem = mem + x[t]; spike = (mem - 1 > 0); mem = spike ? 0 : mem.
//
// v3: latency-structure fix. v2 counters showed 2.4 TB/s @ 84us with VALUBusy
// 4% -> NOT BW-bound; the loop was `load; wait vmcnt(0); compute; store(nt)`
// with VGPR=16 (one load in flight), and in-order vmcnt made each load-consume
// wait also drain the previous NT store (HBM-latency retire).
// Fix: CHUNKS=4 float4 groups per thread (grid 8192->2048 blocks), and issue
// timestep t+1's 4 loads BEFORE timestep t's 4 stores, so the load-consume
// waitcnt (vmcnt(4)) never covers the younger stores. 4-8 loads in flight/wave.
// NT stores kept: no RFO, no L3 pollution of x.

#define LIF_T 4
#define CHUNKS 4

typedef float f32x4 __attribute__((ext_vector_type(4)));

__global__ __launch_bounds__(256) void
lif_spike_kernel(const float* __restrict__ x, float* __restrict__ out,
                 int n_vec, int stride /* = total threads */) {
    const int tid0 = blockIdx.x * blockDim.x + threadIdx.x;
    const f32x4* __restrict__ xv = reinterpret_cast<const f32x4*>(x);
    f32x4* __restrict__ ov = reinterpret_cast<f32x4*>(out);

    int idx[CHUNKS];
    bool ok[CHUNKS];
#pragma unroll
    for (int c = 0; c < CHUNKS; ++c) {
        idx[c] = tid0 + c * stride;
        ok[c] = idx[c] < n_vec;
    }

    f32x4 mem[CHUNKS];
    f32x4 cur[CHUNKS];
    f32x4 nxt[CHUNKS];
#pragma unroll
    for (int c = 0; c < CHUNKS; ++c) mem[c] = (f32x4){0.f, 0.f, 0.f, 0.f};

    // prologue: issue all t=0 loads (4 independent loads in flight)
#pragma unroll
    for (int c = 0; c < CHUNKS; ++c)
        if (ok[c]) cur[c] = xv[idx[c]];

#pragma unroll
    for (int t = 0; t < LIF_T; ++t) {
        // issue next timestep's loads BEFORE this timestep's stores:
        // consuming them later waits only on loads (stores are younger in vmcnt)
        if (t + 1 < LIF_T) {
#pragma unroll
            for (int c = 0; c < CHUNKS; ++c)
                if (ok[c]) nxt[c] = xv[(size_t)(t + 1) * n_vec + idx[c]];
        }

#pragma unroll
        for (int c = 0; c < CHUNKS; ++c) {
            mem[c].x += cur[c].x;
            mem[c].y += cur[c].y;
            mem[c].z += cur[c].z;
            mem[c].w += cur[c].w;

            f32x4 sp;
            sp.x = (mem[c].x > 1.0f) ? 1.0f : 0.0f;
            sp.y = (mem[c].y > 1.0f) ? 1.0f : 0.0f;
            sp.z = (mem[c].z > 1.0f) ? 1.0f : 0.0f;
            sp.w = (mem[c].w > 1.0f) ? 1.0f : 0.0f;

            mem[c].x = (sp.x > 0.f) ? 0.f : mem[c].x;
            mem[c].y = (sp.y > 0.f) ? 0.f : mem[c].y;
            mem[c].z = (sp.z > 0.f) ? 0.f : mem[c].z;
            mem[c].w = (sp.w > 0.f) ? 0.f : mem[c].w;

            if (ok[c])
                __builtin_nontemporal_store(sp, &ov[(size_t)t * n_vec + idx[c]]);
        }

#pragma unroll
        for (int c = 0; c < CHUNKS; ++c) cur[c] = nxt[c];
    }
}

extern "C" void kernel_launch(void* const* d_in, const int* in_sizes, int n_in,
                              void* d_out, int out_size, void* d_ws, size_t ws_size,
                              hipStream_t stream) {
    const float* x = (const float*)d_in[0];
    float* out = (float*)d_out;

    int n = out_size / LIF_T;      // elements per timestep (8,388,608)
    int n_vec = n / 4;             // float4 groups per timestep (2,097,152)

    const int block = 256;
    int grid = (n_vec + block * CHUNKS - 1) / (block * CHUNKS);  // 2048
    int stride = grid * block;                                   // 524,288
    lif_spike_kernel<<<grid, block, 0, stream>>>(x, out, n_vec, stride);
}